// Round 4
// baseline (317.344 us; speedup 1.0000x reference)
//
#include <hip/hip_runtime.h>

// GCN layer: out = relu( segment_mean(feature[edge_src], edge_dst) @ W^T + b )
// N=100000 nodes, E=1200000 edges, 64 feats in/out, all f32.
//
// Round 4: gather reworked to 16-lane x float4 rows (4 edges in flight per
// wave, shfl-xor cross-group reduce); top-level scan folded into scan_apply.

constexpr int kNodes = 100000;
constexpr int kEdges = 1200000;
constexpr int kFeats = 64;

// Workspace layout (int elements; base 16B-aligned)
constexpr int kWsCounts    = 0;        // [100000]
constexpr int kWsOffsets   = 100000;   // [100001]
constexpr int kWsCursor    = 200008;   // [100000]
constexpr int kWsSorted    = 300008;   // [1200000]
constexpr int kWsBlockSums = 1500008;  // [128]

constexpr int kScanBlocks = (kNodes + 1023) / 1024;  // 98

// ---------------------------------------------------------------------------
// Kernel 1: histogram of destination degrees. 1.2M scattered int atomics
// (0.4 MB table -> L2-resident).
// ---------------------------------------------------------------------------
__global__ __launch_bounds__(256) void gcn_hist(
    const int* __restrict__ dst, int* __restrict__ counts) {
  int e = blockIdx.x * 256 + threadIdx.x;
  if (e < kEdges) atomicAdd(&counts[dst[e]], 1);
}

// ---------------------------------------------------------------------------
// Kernel 2a: per-block sums of counts (1024 elems/block, int4 loads).
// ---------------------------------------------------------------------------
__global__ __launch_bounds__(256) void gcn_scan_reduce(
    const int* __restrict__ counts, int* __restrict__ blocksums) {
  __shared__ int sm[256];
  const int t = threadIdx.x;
  const int base = blockIdx.x * 1024 + t * 4;
  int s = 0;
  if (base + 3 < kNodes) {
    int4 v = *(const int4*)(counts + base);
    s = v.x + v.y + v.z + v.w;
  } else {
    for (int i = 0; i < 4; ++i)
      if (base + i < kNodes) s += counts[base + i];
  }
  sm[t] = s;
  __syncthreads();
  for (int off = 128; off > 0; off >>= 1) {
    if (t < off) sm[t] += sm[t + off];
    __syncthreads();
  }
  if (t == 0) blocksums[blockIdx.x] = sm[0];
}

// ---------------------------------------------------------------------------
// Kernel 2b: full exclusive scan. Each block computes its own base via a
// masked reduction of blocksums[0..blockIdx-1] (98 ints -- trivial), then
// block-local scan. Writes offsets[i] and cursor[i].
// ---------------------------------------------------------------------------
__global__ __launch_bounds__(256) void gcn_scan_apply(
    const int* __restrict__ counts, const int* __restrict__ blocksums,
    int* __restrict__ offsets, int* __restrict__ cursor) {
  __shared__ int sm[256];
  __shared__ int smbase[256];
  const int t = threadIdx.x;
  const int base = blockIdx.x * 1024 + t * 4;

  // --- base = sum of blocksums[i] for i < blockIdx.x ---
  smbase[t] = (t < blockIdx.x && t < kScanBlocks) ? blocksums[t] : 0;
  __syncthreads();
  for (int off = 128; off > 0; off >>= 1) {
    if (t < off) smbase[t] += smbase[t + off];
    __syncthreads();
  }
  const int blockbase = smbase[0];
  __syncthreads();

  // --- block-local exclusive scan over per-thread sums of 4 ---
  int v0 = 0, v1 = 0, v2 = 0, v3 = 0;
  if (base + 3 < kNodes) {
    int4 v = *(const int4*)(counts + base);
    v0 = v.x; v1 = v.y; v2 = v.z; v3 = v.w;
  } else {
    if (base + 0 < kNodes) v0 = counts[base + 0];
    if (base + 1 < kNodes) v1 = counts[base + 1];
    if (base + 2 < kNodes) v2 = counts[base + 2];
    if (base + 3 < kNodes) v3 = counts[base + 3];
  }
  const int s = v0 + v1 + v2 + v3;
  sm[t] = s;
  __syncthreads();
  for (int off = 1; off < 256; off <<= 1) {
    int v = (t >= off) ? sm[t - off] : 0;
    __syncthreads();
    sm[t] += v;
    __syncthreads();
  }
  int run = blockbase + sm[t] - s;  // exclusive base for this thread

  if (base + 0 < kNodes) { offsets[base + 0] = run; cursor[base + 0] = run; run += v0; }
  if (base + 1 < kNodes) { offsets[base + 1] = run; cursor[base + 1] = run; run += v1; }
  if (base + 2 < kNodes) { offsets[base + 2] = run; cursor[base + 2] = run; run += v2; }
  if (base + 3 < kNodes) { offsets[base + 3] = run; cursor[base + 3] = run; }

  if (blockIdx.x == 0 && t == 0) offsets[kNodes] = kEdges;
}

// ---------------------------------------------------------------------------
// Kernel 3: scatter edge source-ids into CSR order. 1.2M int atomics.
// ---------------------------------------------------------------------------
__global__ __launch_bounds__(256) void gcn_fill(
    const int* __restrict__ src, const int* __restrict__ dst,
    int* __restrict__ cursor, int* __restrict__ sorted_src) {
  int e = blockIdx.x * 256 + threadIdx.x;
  if (e < kEdges) {
    int pos = atomicAdd(&cursor[dst[e]], 1);
    sorted_src[pos] = src[e];
  }
}

// ---------------------------------------------------------------------------
// Kernel 4: fused gather-mean + linear + relu. One wave per node.
// Gather: 16 lanes x float4 per source row, 4 edges in flight per wave
// iteration (1 KB per wave-load-instr). Cross-group reduce via shfl_xor.
// Apply: h -> LDS broadcast, Wt transposed+padded in LDS, out=relu(h.Wt+b).
// ---------------------------------------------------------------------------
__global__ __launch_bounds__(256) void gcn_gather_apply(
    const float4* __restrict__ feat4,   // [kNodes*16] float4 view
    const int*    __restrict__ offsets,
    const int*    __restrict__ sorted_src,
    const float*  __restrict__ W,       // [64][64] row-major W[o][d]
    const float*  __restrict__ b,       // [64]
    float*        __restrict__ out) {   // [kNodes][64]
  __shared__ float Wt[64 * 65];         // Wt[d*65+o] = W[o*64+d]
  __shared__ float hs[4][64];

  const int tid = threadIdx.x;
  #pragma unroll
  for (int k = 0; k < 16; ++k) {
    int idx = k * 256 + tid;
    Wt[(idx & 63) * 65 + (idx >> 6)] = W[idx];
  }

  const int wave = tid >> 6;
  const int lane = tid & 63;
  const int g = lane >> 4;   // edge slot 0..3
  const int c = lane & 15;   // float4 chunk of the row
  const int n = blockIdx.x * 4 + wave;

  if (n < kNodes) {
    const int o0 = offsets[n];
    const int o1 = offsets[n + 1];
    float ax = 0.f, ay = 0.f, az = 0.f, aw = 0.f;
    for (int j = o0; j < o1; j += 4) {
      int idx = j + g;
      bool valid = idx < o1;
      int s = sorted_src[valid ? idx : o1 - 1];
      float4 v = feat4[(size_t)s * 16 + c];
      if (valid) { ax += v.x; ay += v.y; az += v.z; aw += v.w; }
    }
    // reduce across the 4 edge-groups (lanes xor 16, 32)
    #pragma unroll
    for (int m = 16; m < 64; m <<= 1) {
      ax += __shfl_xor(ax, m, 64);
      ay += __shfl_xor(ay, m, 64);
      az += __shfl_xor(az, m, 64);
      aw += __shfl_xor(aw, m, 64);
    }
    int dg = o1 - o0;
    float inv = 1.0f / (float)(dg > 1 ? dg : 1);
    if (g == 0) {
      hs[wave][c * 4 + 0] = ax * inv;
      hs[wave][c * 4 + 1] = ay * inv;
      hs[wave][c * 4 + 2] = az * inv;
      hs[wave][c * 4 + 3] = aw * inv;
    }
  }
  __syncthreads();

  if (n < kNodes) {
    float acc = b[lane];
    #pragma unroll
    for (int d = 0; d < 64; ++d) acc += hs[wave][d] * Wt[d * 65 + lane];
    out[(size_t)n * 64 + lane] = acc > 0.0f ? acc : 0.0f;
  }
}

// ---------------------------------------------------------------------------
extern "C" void kernel_launch(void* const* d_in, const int* in_sizes, int n_in,
                              void* d_out, int out_size, void* d_ws, size_t ws_size,
                              hipStream_t stream) {
  const float* feature  = (const float*)d_in[0];
  const int*   edge_src = (const int*)  d_in[1];
  const int*   edge_dst = (const int*)  d_in[2];
  const float* W        = (const float*)d_in[3];
  const float* b        = (const float*)d_in[4];

  float* out = (float*)d_out;
  int* ws_i = (int*)d_ws;
  int* counts     = ws_i + kWsCounts;
  int* offsets    = ws_i + kWsOffsets;
  int* cursor     = ws_i + kWsCursor;
  int* sorted_src = ws_i + kWsSorted;
  int* blocksums  = ws_i + kWsBlockSums;

  hipMemsetAsync(counts, 0, (size_t)kNodes * sizeof(int), stream);

  gcn_hist<<<(kEdges + 255) / 256, 256, 0, stream>>>(edge_dst, counts);

  gcn_scan_reduce<<<kScanBlocks, 256, 0, stream>>>(counts, blocksums);
  gcn_scan_apply<<<kScanBlocks, 256, 0, stream>>>(counts, blocksums, offsets, cursor);

  gcn_fill<<<(kEdges + 255) / 256, 256, 0, stream>>>(edge_src, edge_dst, cursor, sorted_src);

  gcn_gather_apply<<<(kNodes + 3) / 4, 256, 0, stream>>>(
      (const float4*)feature, offsets, sorted_src, W, b, out);
}